// Round 5
// baseline (679.551 us; speedup 1.0000x reference)
//
#include <hip/hip_runtime.h>
#include <hip/hip_bf16.h>

#define NEG 0.2f
#define NBMAX 512      // max buckets; block size of kP
#define BCAP 12288     // per-bucket capacity: mean 8192 + 45 sigma
#define TILE 8192      // edges per stage-1 block

// ---------- kP: bucket partition with LDS counting sort; packed = (src<<8)|(dst&255) ----------
__global__ void __launch_bounds__(512) kP_bucket(
    const int* __restrict__ src, const int* __restrict__ dst,
    int* __restrict__ gcur, unsigned int* __restrict__ packed, int E, int NB)
{
    __shared__ int hist[NBMAX], lofs[NBMAX], gbase[NBMAX], cur[NBMAX], s[NBMAX];
    __shared__ unsigned int stage[TILE];
    int tid = threadIdx.x;
    hist[tid] = 0;
    __syncthreads();
    int t0 = blockIdx.x * TILE;
    int tend = t0 + TILE; if (tend > E) tend = E;
    for (int i = t0 + tid; i < tend; i += 512)
        atomicAdd(&hist[dst[i] >> 8], 1);
    __syncthreads();
    // exclusive scan of hist (512 entries)
    int v = hist[tid];
    s[tid] = v;
    __syncthreads();
    for (int off = 1; off < NBMAX; off <<= 1) {
        int t = (tid >= off) ? s[tid - off] : 0;
        __syncthreads();
        s[tid] += t;
        __syncthreads();
    }
    lofs[tid] = s[tid] - v;
    gbase[tid] = v ? atomicAdd(&gcur[tid], v) : 0;  // one global atomic per (block,bucket)
    cur[tid] = 0;
    __syncthreads();
    // stage edges ordered by bucket
    for (int i = t0 + tid; i < tend; i += 512) {
        int d = dst[i];
        int j = d >> 8;
        int pos = lofs[j] + atomicAdd(&cur[j], 1);
        stage[pos] = ((unsigned)src[i] << 8) | (unsigned)(d & 255);
    }
    __syncthreads();
    // write contiguous runs: wave w handles buckets w, w+8, ...
    int wave = tid >> 6, lane = tid & 63;
    for (int j = wave; j < NB; j += 8) {
        int h = hist[j], lo = lofs[j], gb = gbase[j];
        for (int k = lane; k < h; k += 64) {
            int gp = gb + k;
            if (gp < BCAP) packed[(size_t)j * BCAP + gp] = stage[lo + k];
        }
    }
}

// ---------- kL1: per-bucket layer-1 (LDS atomics) + fused k3 finalize ----------
__global__ void __launch_bounds__(256) kL1(
    const int* __restrict__ gcur, const unsigned int* __restrict__ packed,
    const float* __restrict__ x,
    const float* __restrict__ W1, const float* __restrict__ as1, const float* __restrict__ ad1,
    const float* __restrict__ b1, const float* __restrict__ W2,
    const float* __restrict__ as2w, const float* __restrict__ ad2w,
    float* __restrict__ h2, float* __restrict__ as2, float* __restrict__ ad2, int N)
{
    __shared__ float num_s[8][256], den_s[8][256];
    __shared__ float x_s[256];
    __shared__ float S1[8], D1[8];
    __shared__ float sW1[64], sb1[64], sW2[512], sas[8], sad[8];
    int tid = threadIdx.x, b = blockIdx.x;
    int node = b * 256 + tid;
    if (tid < 8) {
        float sv = 0.f, dv = 0.f;
        for (int c = 0; c < 8; ++c) {
            float w = W1[tid * 8 + c];
            sv += w * as1[tid * 8 + c];
            dv += w * ad1[tid * 8 + c];
        }
        S1[tid] = sv; D1[tid] = dv;
        sas[tid] = as2w[tid]; sad[tid] = ad2w[tid];
    }
    for (int i = tid; i < 64; i += 256) { sW1[i] = W1[i]; sb1[i] = b1[i]; }
    for (int i = tid; i < 512; i += 256) sW2[i] = W2[i];
    float xv = (node < N) ? x[node] : 0.f;
    x_s[tid] = xv;
    __syncthreads();
    float s1r[8], d1r[8];
    #pragma unroll
    for (int h = 0; h < 8; ++h) { s1r[h] = S1[h]; d1r[h] = D1[h]; }
    // init accumulators with self-loop
    #pragma unroll
    for (int h = 0; h < 8; ++h) {
        float t = xv * (s1r[h] + d1r[h]);
        t = fmaxf(t, NEG * t);                 // leaky_relu, NEG<1
        float w = __expf(t);
        den_s[h][tid] = w;
        num_s[h][tid] = w * xv;
    }
    __syncthreads();
    int cnt = gcur[b]; if (cnt > BCAP) cnt = BCAP;
    const unsigned int* pk = packed + (size_t)b * BCAP;
    for (int i = tid; i < cnt; i += 256) {
        unsigned p = pk[i];
        int sidx = (int)(p >> 8);
        int dl = (int)(p & 255);
        float xsv = x[sidx];
        float xdv = x_s[dl];
        #pragma unroll
        for (int h = 0; h < 8; ++h) {
            float t = xsv * s1r[h] + xdv * d1r[h];
            t = fmaxf(t, NEG * t);
            float w = __expf(t);
            atomicAdd(&den_s[h][dl], w);
            atomicAdd(&num_s[h][dl], w * xsv);
        }
    }
    __syncthreads();
    if (node >= N) return;
    // fused k3: softmax-normalize, +b1, elu, @W2, attention scalars
    float h1[64];
    #pragma unroll
    for (int h = 0; h < 8; ++h) {
        float agg = num_s[h][tid] / (den_s[h][tid] + 1e-16f);
        #pragma unroll
        for (int c = 0; c < 8; ++c) {
            float vv = agg * sW1[h * 8 + c] + sb1[h * 8 + c];
            h1[h * 8 + c] = vv > 0.f ? vv : (__expf(vv) - 1.f);
        }
    }
    float o[8] = {0,0,0,0,0,0,0,0};
    #pragma unroll
    for (int k = 0; k < 64; ++k) {
        float hv = h1[k];
        #pragma unroll
        for (int c = 0; c < 8; ++c) o[c] += hv * sW2[k * 8 + c];
    }
    float as_ = 0.f, ad_ = 0.f;
    #pragma unroll
    for (int c = 0; c < 8; ++c) {
        as_ += o[c] * sas[c];
        ad_ += o[c] * sad[c];
        h2[(size_t)node * 8 + c] = o[c];
    }
    as2[node] = as_; ad2[node] = ad_;
}

// ---------- kL2: per-bucket layer-2 (LDS atomics), writes out2 = num/den ----------
__global__ void __launch_bounds__(256) kL2(
    const int* __restrict__ gcur, const unsigned int* __restrict__ packed,
    const float* __restrict__ as2, const float* __restrict__ ad2,
    const float* __restrict__ h2,
    float* __restrict__ out2, int N)
{
    __shared__ float num_s[8][256];
    __shared__ float den_s[256], ad_s[256];
    int tid = threadIdx.x, b = blockIdx.x;
    int node = b * 256 + tid;
    float adv = (node < N) ? ad2[node] : 0.f;
    ad_s[tid] = adv;
    float asv = (node < N) ? as2[node] : 0.f;
    float t = asv + adv;                       // self loop
    t = fmaxf(t, NEG * t);
    float w = __expf(t);
    den_s[tid] = w;
    #pragma unroll
    for (int c = 0; c < 8; ++c)
        num_s[c][tid] = (node < N) ? w * h2[(size_t)node * 8 + c] : 0.f;
    __syncthreads();
    int cnt = gcur[b]; if (cnt > BCAP) cnt = BCAP;
    const unsigned int* pk = packed + (size_t)b * BCAP;
    for (int i = tid; i < cnt; i += 256) {
        unsigned p = pk[i];
        int sidx = (int)(p >> 8);
        int dl = (int)(p & 255);
        float e = as2[sidx] + ad_s[dl];
        e = fmaxf(e, NEG * e);
        float ww = __expf(e);
        atomicAdd(&den_s[dl], ww);
        const float4* hp = (const float4*)(h2 + (size_t)sidx * 8);
        float4 a = hp[0], bb = hp[1];
        atomicAdd(&num_s[0][dl], ww * a.x);
        atomicAdd(&num_s[1][dl], ww * a.y);
        atomicAdd(&num_s[2][dl], ww * a.z);
        atomicAdd(&num_s[3][dl], ww * a.w);
        atomicAdd(&num_s[4][dl], ww * bb.x);
        atomicAdd(&num_s[5][dl], ww * bb.y);
        atomicAdd(&num_s[6][dl], ww * bb.z);
        atomicAdd(&num_s[7][dl], ww * bb.w);
    }
    __syncthreads();
    if (node >= N) return;
    float dv = den_s[tid] + 1e-16f;
    #pragma unroll
    for (int c = 0; c < 8; ++c)
        out2[(size_t)node * 8 + c] = num_s[c][tid] / dv;
}

// ---------- kB: graph start offsets from sorted batch ----------
__global__ void __launch_bounds__(256) kB_starts(
    const int* __restrict__ batch, int* __restrict__ gstart, int N, int G)
{
    int n = blockIdx.x * blockDim.x + threadIdx.x;
    if (n >= N) return;
    int b0 = batch[n];
    if (n == 0) {
        for (int g = 0; g <= b0; ++g) gstart[g] = 0;
    } else {
        int bp = batch[n - 1];
        for (int g = bp + 1; g <= b0; ++g) gstart[g] = n;
    }
    if (n == N - 1) {
        for (int g = b0 + 1; g <= G; ++g) gstart[g] = N;
    }
}

// ---------- kPool: one wave per graph — mean pool + b2 + linear + log_softmax ----------
__global__ void __launch_bounds__(256) kPool(
    const float* __restrict__ out2, const int* __restrict__ gstart,
    const float* __restrict__ b2v,
    const float* __restrict__ lin_w, const float* __restrict__ lin_b,
    float* __restrict__ out, int G)
{
    __shared__ float sw[80], sb[10], sb2[8];
    if (threadIdx.x < 80) sw[threadIdx.x] = lin_w[threadIdx.x];
    if (threadIdx.x < 10) sb[threadIdx.x] = lin_b[threadIdx.x];
    if (threadIdx.x < 8)  sb2[threadIdx.x] = b2v[threadIdx.x];
    __syncthreads();
    int wid = (blockIdx.x * blockDim.x + threadIdx.x) >> 6;
    if (wid >= G) return;
    int lane = threadIdx.x & 63;
    int ch = lane & 7, sub = lane >> 3;
    int start = gstart[wid], end = gstart[wid + 1];
    int cntn = end - start;
    float acc = 0.f;
    for (int i = start + sub; i < end; i += 8)
        acc += out2[(size_t)i * 8 + ch];       // fully coalesced: addr = start*8 + lane + 64k
    acc += __shfl_down(acc, 32, 64);
    acc += __shfl_down(acc, 16, 64);
    acc += __shfl_down(acc, 8, 64);
    // lanes 0..7 hold channel totals; broadcast
    float inv = (cntn > 0) ? 1.f / (float)cntn : 0.f;
    float p[8];
    #pragma unroll
    for (int i = 0; i < 8; ++i) {
        float tt = __shfl(acc, i, 64);
        p[i] = (cntn > 0) ? (tt * inv + sb2[i]) : 0.f;
    }
    float l[10]; float m = -1e30f;
    #pragma unroll
    for (int j = 0; j < 10; ++j) {
        float v = sb[j];
        #pragma unroll
        for (int i = 0; i < 8; ++i) v += p[i] * sw[i * 10 + j];
        l[j] = v; m = v > m ? v : m;
    }
    float sum = 0.f;
    #pragma unroll
    for (int j = 0; j < 10; ++j) sum += __expf(l[j] - m);
    float lse = m + __logf(sum);
    if (lane < 10) out[(size_t)wid * 10 + lane] = l[lane] - lse;
}

extern "C" void kernel_launch(void* const* d_in, const int* in_sizes, int n_in,
                              void* d_out, int out_size, void* d_ws, size_t ws_size,
                              hipStream_t stream) {
    const float* x    = (const float*)d_in[0];
    const int*   ei   = (const int*)d_in[1];
    const int*   batch= (const int*)d_in[2];
    const float* W1   = (const float*)d_in[4];
    const float* as1  = (const float*)d_in[5];
    const float* ad1  = (const float*)d_in[6];
    const float* b1   = (const float*)d_in[7];
    const float* W2   = (const float*)d_in[8];
    const float* as2w = (const float*)d_in[9];
    const float* ad2w = (const float*)d_in[10];
    const float* b2v  = (const float*)d_in[11];
    const float* lw   = (const float*)d_in[12];
    const float* lb   = (const float*)d_in[13];
    float* out = (float*)d_out;

    const int N = in_sizes[0];            // 100000
    const int E = in_sizes[1] / 2;        // 3200000
    const int G = out_size / 10;          // 512
    const int* srcI = ei;
    const int* dstI = ei + E;
    const int NB = (N + 255) >> 8;        // 391 buckets of 256 nodes

    // workspace layout (16B-aligned sections)
    int*   gcur = (int*)d_ws;                                // 512
    unsigned int* packed = (unsigned int*)(gcur + 512);      // NB*BCAP
    float* h2   = (float*)(packed + (size_t)NB * BCAP);      // 8N
    float* as2  = h2 + (size_t)8 * N;                        // N
    float* ad2  = as2 + N;                                   // N
    float* out2 = ad2 + N;                                   // 8N
    int*   gstart = (int*)(out2 + (size_t)8 * N);            // G+1

    const int B = 256;
    hipMemsetAsync(gcur, 0, 512 * sizeof(int), stream);

    kP_bucket<<<(E + TILE - 1) / TILE, 512, 0, stream>>>(srcI, dstI, gcur, packed, E, NB);
    kB_starts<<<(N + B - 1) / B, B, 0, stream>>>(batch, gstart, N, G);
    kL1<<<NB, B, 0, stream>>>(gcur, packed, x, W1, as1, ad1, b1, W2, as2w, ad2w,
                              h2, as2, ad2, N);
    kL2<<<NB, B, 0, stream>>>(gcur, packed, as2, ad2, h2, out2, N);
    kPool<<<(G * 64 + B - 1) / B, B, 0, stream>>>(out2, gstart, b2v, lw, lb, out, G);
}

// Round 6
// 230.071 us; speedup vs baseline: 2.9536x; 2.9536x over previous
//
#include <hip/hip_runtime.h>
#include <hip/hip_bf16.h>

#define HEADS 8
#define HID 8
#define NEG 0.2f

#define NBMAX 512      // max buckets; block size of kP
#define BCAP 12288     // per-bucket capacity: mean 8192 + 45 sigma
#define TILE 8192      // edges per stage-1 block

// ---------- kP: bucket partition with LDS counting sort; packed = (src<<8)|(dst&255) ----------
__global__ void __launch_bounds__(512) kP_bucket(
    const int* __restrict__ src, const int* __restrict__ dst,
    int* __restrict__ gcur, unsigned int* __restrict__ packed, int E, int NB)
{
    __shared__ int hist[NBMAX], lofs[NBMAX], gbase[NBMAX], cur[NBMAX], s[NBMAX];
    __shared__ unsigned int stage[TILE];
    int tid = threadIdx.x;
    hist[tid] = 0;
    __syncthreads();
    int t0 = blockIdx.x * TILE;
    int tend = t0 + TILE; if (tend > E) tend = E;
    for (int i = t0 + tid; i < tend; i += 512)
        atomicAdd(&hist[dst[i] >> 8], 1);
    __syncthreads();
    // exclusive scan of hist (512 entries)
    int v = hist[tid];
    s[tid] = v;
    __syncthreads();
    for (int off = 1; off < NBMAX; off <<= 1) {
        int t = (tid >= off) ? s[tid - off] : 0;
        __syncthreads();
        s[tid] += t;
        __syncthreads();
    }
    lofs[tid] = s[tid] - v;
    gbase[tid] = v ? atomicAdd(&gcur[tid], v) : 0;  // one global atomic per (block,bucket)
    cur[tid] = 0;
    __syncthreads();
    // stage edges ordered by bucket
    for (int i = t0 + tid; i < tend; i += 512) {
        int d = dst[i];
        int j = d >> 8;
        int pos = lofs[j] + atomicAdd(&cur[j], 1);
        stage[pos] = ((unsigned)src[i] << 8) | (unsigned)(d & 255);
    }
    __syncthreads();
    // write contiguous runs: wave w handles buckets w, w+8, ...
    int wave = tid >> 6, lane = tid & 63;
    for (int j = wave; j < NB; j += 8) {
        int h = hist[j], lo = lofs[j], gb = gbase[j];
        for (int k = lane; k < h; k += 64) {
            int gp = gb + k;
            if (gp < BCAP) packed[(size_t)j * BCAP + gp] = stage[lo + k];
        }
    }
}

// ---------- kF: per-bucket fine CSR in LDS; csr written in place over packed ----------
__global__ void __launch_bounds__(256) kF_fine(
    const int* __restrict__ gcur, unsigned int* packed,
    int* __restrict__ rowS, int* __restrict__ rowE, int N)
{
    __shared__ int hist[256], roff[256], cur[256];
    __shared__ int stage[BCAP];
    int b = blockIdx.x;
    size_t base = (size_t)b * BCAP;
    int cnt = gcur[b]; if (cnt > BCAP) cnt = BCAP;
    int tid = threadIdx.x;
    hist[tid] = 0;
    __syncthreads();
    for (int i = tid; i < cnt; i += 256)
        atomicAdd(&hist[packed[base + i] & 255], 1);
    __syncthreads();
    int v = hist[tid];
    roff[tid] = v;
    __syncthreads();
    for (int off = 1; off < 256; off <<= 1) {
        int t = (tid >= off) ? roff[tid - off] : 0;
        __syncthreads();
        roff[tid] += t;
        __syncthreads();
    }
    int excl = roff[tid] - v;       // exclusive scan within bucket
    cur[tid] = excl;
    int node = b * 256 + tid;
    if (node < N) { rowS[node] = (int)base + excl; rowE[node] = (int)base + excl + v; }
    __syncthreads();
    for (int i = tid; i < cnt; i += 256) {
        unsigned p = packed[base + i];
        int pos = atomicAdd(&cur[p & 255], 1);       // LDS cursor
        stage[pos] = (int)(p >> 8);                  // src
    }
    __syncthreads();
    for (int i = tid; i < cnt; i += 256)             // coalesced csr write (aliases packed)
        packed[base + i] = (unsigned)stage[i];
}

// ---------- layer-1 gather: 8 lanes per dst node, no atomics ----------
__global__ void __launch_bounds__(256) kG1_gather(
    const int* __restrict__ rowS, const int* __restrict__ rowE,
    const unsigned int* __restrict__ csr,
    const float* __restrict__ x,
    const float* __restrict__ W1, const float* __restrict__ as1, const float* __restrict__ ad1,
    float* __restrict__ num1, float* __restrict__ den1, int N)
{
    __shared__ float S1[HEADS], D1[HEADS];
    if (threadIdx.x < HEADS) {
        float s = 0.f, d = 0.f;
        for (int c = 0; c < HID; ++c) {
            float w = W1[threadIdx.x * HID + c];
            s += w * as1[threadIdx.x * HID + c];
            d += w * ad1[threadIdx.x * HID + c];
        }
        S1[threadIdx.x] = s; D1[threadIdx.x] = d;
    }
    __syncthreads();
    int t = blockIdx.x * blockDim.x + threadIdx.x;
    int node = t >> 3, lane = t & 7;
    if (node >= N) return;
    float xdv = x[node];
    float den[8] = {0,0,0,0,0,0,0,0}, num[8] = {0,0,0,0,0,0,0,0};
    if (lane == 0) {            // self loop
        #pragma unroll
        for (int h = 0; h < 8; ++h) {
            float e = xdv * (S1[h] + D1[h]);
            e = fmaxf(e, NEG * e);
            float w = __expf(e);
            den[h] = w; num[h] = w * xdv;
        }
    }
    int start = rowS[node], end = rowE[node];
    for (int j = start + lane; j < end; j += 8) {
        int s = (int)csr[j];
        float xsv = x[s];
        #pragma unroll
        for (int h = 0; h < 8; ++h) {
            float e = xsv * S1[h] + xdv * D1[h];
            e = fmaxf(e, NEG * e);
            float w = __expf(e);
            den[h] += w; num[h] += w * xsv;
        }
    }
    #pragma unroll
    for (int off = 4; off >= 1; off >>= 1) {
        #pragma unroll
        for (int h = 0; h < 8; ++h) {
            den[h] += __shfl_down(den[h], off, 8);
            num[h] += __shfl_down(num[h], off, 8);
        }
    }
    if (lane == 0) {
        #pragma unroll
        for (int h = 0; h < 8; ++h) {
            num1[node * 8 + h] = num[h];
            den1[node * 8 + h] = den[h];
        }
    }
}

// ---------- k3: finalize layer 1, h2 = elu(h1)@W2, attention scalars ----------
__global__ void __launch_bounds__(256) k3_node_mid(
    const float* __restrict__ num1, const float* __restrict__ den1,
    const float* __restrict__ W1, const float* __restrict__ b1,
    const float* __restrict__ W2,
    const float* __restrict__ as2w, const float* __restrict__ ad2w,
    float* __restrict__ h2, float* __restrict__ as2, float* __restrict__ ad2, int N)
{
    __shared__ float sW1[64], sb1[64], sW2[512], sas[8], sad[8];
    for (int i = threadIdx.x; i < 64; i += blockDim.x) { sW1[i] = W1[i]; sb1[i] = b1[i]; }
    for (int i = threadIdx.x; i < 512; i += blockDim.x) sW2[i] = W2[i];
    if (threadIdx.x < 8) { sas[threadIdx.x] = as2w[threadIdx.x]; sad[threadIdx.x] = ad2w[threadIdx.x]; }
    __syncthreads();
    int n = blockIdx.x * blockDim.x + threadIdx.x;
    if (n >= N) return;
    float h1[64];
    #pragma unroll
    for (int h = 0; h < 8; ++h) {
        float agg = num1[n * 8 + h] / (den1[n * 8 + h] + 1e-16f);
        #pragma unroll
        for (int c = 0; c < 8; ++c) {
            float v = agg * sW1[h * 8 + c] + sb1[h * 8 + c];
            h1[h * 8 + c] = v > 0.f ? v : (__expf(v) - 1.f);   // elu
        }
    }
    float o[8] = {0,0,0,0,0,0,0,0};
    #pragma unroll
    for (int k = 0; k < 64; ++k) {
        float hv = h1[k];
        #pragma unroll
        for (int c = 0; c < 8; ++c) o[c] += hv * sW2[k * 8 + c];
    }
    float as_ = 0.f, ad_ = 0.f;
    #pragma unroll
    for (int c = 0; c < 8; ++c) {
        as_ += o[c] * sas[c];
        ad_ += o[c] * sad[c];
        h2[(size_t)n * 8 + c] = o[c];
    }
    as2[n] = as_; ad2[n] = ad_;
}

// ---------- layer-2 gather: 8 lanes per dst node, no atomics ----------
__global__ void __launch_bounds__(256) kG2_gather(
    const int* __restrict__ rowS, const int* __restrict__ rowE,
    const unsigned int* __restrict__ csr,
    const float* __restrict__ as2, const float* __restrict__ ad2,
    const float* __restrict__ h2,
    float* __restrict__ out2, int N)
{
    int t = blockIdx.x * blockDim.x + threadIdx.x;
    int node = t >> 3, lane = t & 7;
    if (node >= N) return;
    float add = ad2[node];
    float den = 0.f, num[8] = {0,0,0,0,0,0,0,0};
    if (lane == 0) {            // self loop
        float e = as2[node] + add;
        e = fmaxf(e, NEG * e);
        float w = __expf(e);
        den = w;
        const float4* hp = (const float4*)&h2[(size_t)node * 8];
        float4 a = hp[0], b = hp[1];
        num[0] = w * a.x; num[1] = w * a.y; num[2] = w * a.z; num[3] = w * a.w;
        num[4] = w * b.x; num[5] = w * b.y; num[6] = w * b.z; num[7] = w * b.w;
    }
    int start = rowS[node], end = rowE[node];
    for (int j = start + lane; j < end; j += 8) {
        int s = (int)csr[j];
        float e = as2[s] + add;
        e = fmaxf(e, NEG * e);
        float w = __expf(e);
        den += w;
        const float4* hp = (const float4*)&h2[(size_t)s * 8];
        float4 a = hp[0], b = hp[1];
        num[0] += w * a.x; num[1] += w * a.y; num[2] += w * a.z; num[3] += w * a.w;
        num[4] += w * b.x; num[5] += w * b.y; num[6] += w * b.z; num[7] += w * b.w;
    }
    #pragma unroll
    for (int off = 4; off >= 1; off >>= 1) {
        den += __shfl_down(den, off, 8);
        #pragma unroll
        for (int c = 0; c < 8; ++c) num[c] += __shfl_down(num[c], off, 8);
    }
    if (lane == 0) {
        float dv = den + 1e-16f;
        #pragma unroll
        for (int c = 0; c < 8; ++c) out2[(size_t)node * 8 + c] = num[c] / dv;
    }
}

// ---------- kB: graph start offsets from sorted batch ----------
__global__ void __launch_bounds__(256) kB_starts(
    const int* __restrict__ batch, int* __restrict__ gstart, int N, int G)
{
    int n = blockIdx.x * blockDim.x + threadIdx.x;
    if (n >= N) return;
    int b0 = batch[n];
    if (n == 0) {
        for (int g = 0; g <= b0; ++g) gstart[g] = 0;
    } else {
        int bp = batch[n - 1];
        for (int g = bp + 1; g <= b0; ++g) gstart[g] = n;
    }
    if (n == N - 1) {
        for (int g = b0 + 1; g <= G; ++g) gstart[g] = N;
    }
}

// ---------- kPool: one wave per graph — mean pool + b2 + linear + log_softmax ----------
__global__ void __launch_bounds__(256) kPool(
    const float* __restrict__ out2, const int* __restrict__ gstart,
    const float* __restrict__ b2v,
    const float* __restrict__ lin_w, const float* __restrict__ lin_b,
    float* __restrict__ out, int G)
{
    __shared__ float sw[80], sb[10], sb2[8];
    if (threadIdx.x < 80) sw[threadIdx.x] = lin_w[threadIdx.x];
    if (threadIdx.x < 10) sb[threadIdx.x] = lin_b[threadIdx.x];
    if (threadIdx.x < 8)  sb2[threadIdx.x] = b2v[threadIdx.x];
    __syncthreads();
    int wid = (blockIdx.x * blockDim.x + threadIdx.x) >> 6;
    if (wid >= G) return;
    int lane = threadIdx.x & 63;
    int ch = lane & 7, sub = lane >> 3;
    int start = gstart[wid], end = gstart[wid + 1];
    int cntn = end - start;
    float acc = 0.f;
    for (int i = start + sub; i < end; i += 8)
        acc += out2[(size_t)i * 8 + ch];       // fully coalesced: addr = start*8 + lane + 64k
    acc += __shfl_down(acc, 32, 64);
    acc += __shfl_down(acc, 16, 64);
    acc += __shfl_down(acc, 8, 64);
    float inv = (cntn > 0) ? 1.f / (float)cntn : 0.f;
    float p[8];
    #pragma unroll
    for (int i = 0; i < 8; ++i) {
        float tt = __shfl(acc, i, 64);
        p[i] = (cntn > 0) ? (tt * inv + sb2[i]) : 0.f;
    }
    float l[10]; float m = -1e30f;
    #pragma unroll
    for (int j = 0; j < 10; ++j) {
        float v = sb[j];
        #pragma unroll
        for (int i = 0; i < 8; ++i) v += p[i] * sw[i * 10 + j];
        l[j] = v; m = v > m ? v : m;
    }
    float sum = 0.f;
    #pragma unroll
    for (int j = 0; j < 10; ++j) sum += __expf(l[j] - m);
    float lse = m + __logf(sum);
    if (lane < 10) out[(size_t)wid * 10 + lane] = l[lane] - lse;
}

extern "C" void kernel_launch(void* const* d_in, const int* in_sizes, int n_in,
                              void* d_out, int out_size, void* d_ws, size_t ws_size,
                              hipStream_t stream) {
    const float* x    = (const float*)d_in[0];
    const int*   ei   = (const int*)d_in[1];
    const int*   batch= (const int*)d_in[2];
    const float* W1   = (const float*)d_in[4];
    const float* as1  = (const float*)d_in[5];
    const float* ad1  = (const float*)d_in[6];
    const float* b1   = (const float*)d_in[7];
    const float* W2   = (const float*)d_in[8];
    const float* as2w = (const float*)d_in[9];
    const float* ad2w = (const float*)d_in[10];
    const float* b2v  = (const float*)d_in[11];
    const float* lw   = (const float*)d_in[12];
    const float* lb   = (const float*)d_in[13];
    float* out = (float*)d_out;

    const int N = in_sizes[0];            // 100000
    const int E = in_sizes[1] / 2;        // 3200000
    const int G = out_size / 10;          // 512
    const int* srcI = ei;
    const int* dstI = ei + E;
    const int NB = (N + 255) >> 8;        // 391 buckets of 256 nodes

    // workspace layout
    int*   gcur = (int*)d_ws;                                // 512
    unsigned int* packed = (unsigned int*)(gcur + 512);      // NB*BCAP (csr aliases this)
    int*   rowS = (int*)(packed + (size_t)NB * BCAP);        // N
    int*   rowE = rowS + N;                                  // N
    float* num1 = (float*)(rowE + N);                        // 8N
    float* den1 = num1 + (size_t)8 * N;                      // 8N
    float* h2   = den1 + (size_t)8 * N;                      // 8N
    float* as2  = h2 + (size_t)8 * N;                        // N
    float* ad2  = as2 + N;                                   // N
    float* out2 = ad2 + N;                                   // 8N
    int*   gstart = (int*)(out2 + (size_t)8 * N);            // G+1

    const int B = 256;
    hipMemsetAsync(gcur, 0, 512 * sizeof(int), stream);

    kP_bucket<<<(E + TILE - 1) / TILE, 512, 0, stream>>>(srcI, dstI, gcur, packed, E, NB);
    kB_starts<<<(N + B - 1) / B, B, 0, stream>>>(batch, gstart, N, G);
    kF_fine<<<NB, B, 0, stream>>>(gcur, packed, rowS, rowE, N);
    kG1_gather<<<(N * 8 + B - 1) / B, B, 0, stream>>>(rowS, rowE, packed, x,
                                                      W1, as1, ad1, num1, den1, N);
    k3_node_mid<<<(N + B - 1) / B, B, 0, stream>>>(num1, den1, W1, b1, W2, as2w, ad2w,
                                                   h2, as2, ad2, N);
    kG2_gather<<<(N * 8 + B - 1) / B, B, 0, stream>>>(rowS, rowE, packed, as2, ad2, h2,
                                                      out2, N);
    kPool<<<(G * 64 + B - 1) / B, B, 0, stream>>>(out2, gstart, b2v, lw, lb, out, G);
}